// Round 11
// baseline (18.649 us; speedup 1.0000x reference)
//
#include <hip/hip_runtime.h>

// GradLoss: mean((sobelx(t)-sobelx(o))^2) + mean((sobely(t)-sobely(o))^2)
//         = mean(sobelx(d)^2) + mean(sobely(d)^2), d = t - o   (linearity)
//
// Stage1 (R10 core, tripwire-safe frame): 256 blocks x 512 threads; each of
// the 8 waves owns a FULL 512-col x 8-row strip (8 cols/lane = 2 float4).
// 10 rows loaded / 8 output = 1.25x amplification; 2 shuffles per row
// (lane-boundary halo only, zeroed at image edge); no LDS staging, no hot
// barriers; named-register 4-slot load pipeline + 3-set hs/hd ring (no
// arrays -> no scratch; VGPR must be >>36). Block partial = plain store,
// d_ws fully overwritten each call -> deterministic across graph replays.
// Stage2: 1 block reduces 256 partials -> d_out. (R10's reset-free counter
// tree tripped the determinism tripwire; two-dispatch frame is proven.)

#define BATCH 32
#define HH 512
#define WW 512
#define RW 8                         // output rows per wave
#define TPB 512                      // 8 waves per block
#define NBLK 256                     // 1 block/CU; wave = one strip

__global__ __launch_bounds__(TPB) void sobel_partial_kernel(
    const float* __restrict__ out_img,
    const float* __restrict__ tgt_img,
    float* __restrict__ partials)
{
    const int tid  = threadIdx.x;
    const int lane = tid & 63;
    const int wv   = tid >> 6;                     // 0..7
    // XCD swizzle: each XCD gets 32 consecutive blocks (4 whole images)
    const int b    = (blockIdx.x & 7) * (NBLK / 8) + (blockIdx.x >> 3);
    const int img  = b >> 3;                       // 8 blocks per image
    const int y0   = ((b & 7) * 8 + wv) * RW;      // strip base row
    const size_t base = (size_t)img * HH * WW;
    const float* ob = out_img + base + (lane << 3);
    const float* tb = tgt_img + base + (lane << 3);

    float acc = 0.f;

    // ---- named-register pipeline: 4 load slots, 3 hs/hd ring sets ----
#define DECLL(k) float4 oA##k, oB##k, tA##k, tB##k;
#define DECLH(h) float4 hsA##h, hdA##h, hsB##h, hdB##h;
    DECLL(0) DECLL(1) DECLL(2) DECLL(3)
    DECLH(0) DECLH(1) DECLH(2)

#define LOADR(i, k) {                                                          \
    const int gc_ = min(max(y0 - 1 + (i), 0), HH - 1);                         \
    const float* o_ = ob + (size_t)gc_ * WW;                                   \
    const float* t_ = tb + (size_t)gc_ * WW;                                   \
    oA##k = *(const float4*)o_;  oB##k = *(const float4*)(o_ + 4);             \
    tA##k = *(const float4*)t_;  tB##k = *(const float4*)(t_ + 4);             }

#define DIFFH(i, k, h) {                                                       \
    const float m_ = ((unsigned)(y0 - 1 + (i)) < (unsigned)HH) ? 1.f : 0.f;    \
    const float4 dA_ = make_float4(m_*(tA##k.x-oA##k.x), m_*(tA##k.y-oA##k.y), \
                                   m_*(tA##k.z-oA##k.z), m_*(tA##k.w-oA##k.w));\
    const float4 dB_ = make_float4(m_*(tB##k.x-oB##k.x), m_*(tB##k.y-oB##k.y), \
                                   m_*(tB##k.z-oB##k.z), m_*(tB##k.w-oB##k.w));\
    float dl_ = __shfl_up(dB_.w, 1, 64);   if (lane == 0)  dl_ = 0.f;          \
    float dr_ = __shfl_down(dA_.x, 1, 64); if (lane == 63) dr_ = 0.f;          \
    hsA##h.x = fmaf(2.f, dA_.x, dl_ + dA_.y);   hdA##h.x = dA_.y - dl_;        \
    hsA##h.y = fmaf(2.f, dA_.y, dA_.x + dA_.z); hdA##h.y = dA_.z - dA_.x;      \
    hsA##h.z = fmaf(2.f, dA_.z, dA_.y + dA_.w); hdA##h.z = dA_.w - dA_.y;      \
    hsA##h.w = fmaf(2.f, dA_.w, dA_.z + dB_.x); hdA##h.w = dB_.x - dA_.z;      \
    hsB##h.x = fmaf(2.f, dB_.x, dA_.w + dB_.y); hdB##h.x = dB_.y - dA_.w;      \
    hsB##h.y = fmaf(2.f, dB_.y, dB_.x + dB_.z); hdB##h.y = dB_.z - dB_.x;      \
    hsB##h.z = fmaf(2.f, dB_.z, dB_.y + dB_.w); hdB##h.z = dB_.w - dB_.y;      \
    hsB##h.w = fmaf(2.f, dB_.w, dB_.z + dr_);   hdB##h.w = dr_ - dB_.z;        }

#define VP4(S, T, M, Bt, c) {                                                  \
    const float gx_ = fmaf(2.f, hd##S##M.c, hd##S##T.c + hd##S##Bt.c);         \
    const float gy_ = hs##S##T.c - hs##S##Bt.c;                                \
    acc = fmaf(gx_, gx_, acc); acc = fmaf(gy_, gy_, acc);                      }
#define VPASS(T, M, Bt)                                                        \
    VP4(A, T, M, Bt, x) VP4(A, T, M, Bt, y) VP4(A, T, M, Bt, z)                \
    VP4(A, T, M, Bt, w) VP4(B, T, M, Bt, x) VP4(B, T, M, Bt, y)                \
    VP4(B, T, M, Bt, z) VP4(B, T, M, Bt, w)

    LOADR(0, 0) LOADR(1, 1) LOADR(2, 2) LOADR(3, 3)   // 16 dwordx4 in flight
    DIFFH(0, 0, 0)
    DIFFH(1, 1, 1)
    LOADR(4, 0)
    DIFFH(2, 2, 2) VPASS(0, 1, 2)
    LOADR(5, 1)
    DIFFH(3, 3, 0) VPASS(1, 2, 0)
    LOADR(6, 2)
    DIFFH(4, 0, 1) VPASS(2, 0, 1)
    LOADR(7, 3)
    DIFFH(5, 1, 2) VPASS(0, 1, 2)
    LOADR(8, 0)
    DIFFH(6, 2, 0) VPASS(1, 2, 0)
    LOADR(9, 1)
    DIFFH(7, 3, 1) VPASS(2, 0, 1)
    DIFFH(8, 0, 2) VPASS(0, 1, 2)
    DIFFH(9, 1, 0) VPASS(1, 2, 0)

#undef DECLL
#undef DECLH
#undef LOADR
#undef DIFFH
#undef VP4
#undef VPASS

    // ---- wave reduce -> block reduce -> one plain store per block ----
    #pragma unroll
    for (int off = 32; off > 0; off >>= 1)
        acc += __shfl_down(acc, off, 64);
    __shared__ float wsum[TPB / 64];
    if (lane == 0) wsum[wv] = acc;
    __syncthreads();
    if (tid == 0) {
        float s = 0.f;
        #pragma unroll
        for (int k = 0; k < TPB / 64; ++k) s += wsum[k];
        partials[b] = s;
    }
}

__global__ __launch_bounds__(256) void reduce_partials_kernel(
    const float* __restrict__ partials, float* __restrict__ out)
{
    const int tid = threadIdx.x;
    float s = partials[tid];                       // 256 partials, 256 threads
    #pragma unroll
    for (int off = 32; off > 0; off >>= 1)
        s += __shfl_down(s, off, 64);
    __shared__ float wsum[4];
    if ((tid & 63) == 0) wsum[tid >> 6] = s;
    __syncthreads();
    if (tid == 0)
        out[0] = (wsum[0] + wsum[1] + wsum[2] + wsum[3])
               * (1.0f / ((float)BATCH * HH * WW));
}

extern "C" void kernel_launch(void* const* d_in, const int* in_sizes, int n_in,
                              void* d_out, int out_size, void* d_ws, size_t ws_size,
                              hipStream_t stream) {
    (void)in_sizes; (void)n_in; (void)ws_size; (void)out_size;
    const float* out_img = (const float*)d_in[0];   // "output"
    const float* tgt_img = (const float*)d_in[1];   // "target"
    float* partials = (float*)d_ws;                 // NBLK floats, overwritten
    float* res = (float*)d_out;

    sobel_partial_kernel<<<NBLK, TPB, 0, stream>>>(out_img, tgt_img, partials);
    reduce_partials_kernel<<<1, 256, 0, stream>>>(partials, res);
}